// Round 5
// baseline (122.533 us; speedup 1.0000x reference)
//
#include <hip/hip_runtime.h>
#include <hip/hip_bf16.h>

// Problem constants (match reference setup_inputs)
#define BATCH 8
#define CHN   64
#define GRP   8
#define CG    8      // CHN / GRP
#define HH    128
#define WW    128
#define HW    (HH * WW)   // 16384
// w shape: (B, G, 1, 9, H, W); x/out shape: (B, C, H, W), all fp32.

// MEASUREMENT ROUND: identical kernel to R4, launched TWICE back-to-back.
// dur_us(R5) - dur_us(R4) == one (L3-hot) kernel invocation. Decides whether
// the kernel is at its HBM floor or issue-bound.
__global__ __launch_bounds__(256, 3) void ska_small_kernel(
    const float* __restrict__ x,
    const float* __restrict__ wgt,
    float* __restrict__ out)
{
    int tid = blockIdx.x * blockDim.x + threadIdx.x;
    int q  = tid & 31;           // quad index within row
    int w0 = q * 4;              // aligned float4 column
    int h2 = (tid >> 5) & 63;    // row-pair index
    int g  = (tid >> 11) & 7;
    int b  = tid >> 14;

    const int h0 = h2 * 2;       // even, 0..126
    const int h1 = h0 + 1;       // odd, 1..127

    // ---- 9 dynamic weights for each of the two pixel rows (shared across 8 ch)
    const float* wbase = wgt + ((size_t)(b * GRP + g) * 9) * HW + (size_t)h0 * WW + w0;
    float4 wk0[9], wk1[9];
#pragma unroll
    for (int k = 0; k < 9; ++k) {
        wk0[k] = *(const float4*)(wbase + (size_t)k * HW);
        wk1[k] = *(const float4*)(wbase + (size_t)k * HW + WW);
    }

    // Fold vertical zero-padding into the weights (branchless).
    const float m_top = (h0 > 0)      ? 1.0f : 0.0f;   // row h0's tap-row 0
    const float m_bot = (h1 < HH - 1) ? 1.0f : 0.0f;   // row h1's tap-row 2
#pragma unroll
    for (int j = 0; j < 3; ++j) {
        wk0[j].x     *= m_top; wk0[j].y     *= m_top; wk0[j].z     *= m_top; wk0[j].w     *= m_top;
        wk1[6 + j].x *= m_bot; wk1[6 + j].y *= m_bot; wk1[6 + j].z *= m_bot; wk1[6 + j].w *= m_bot;
    }

    // Horizontal halo via neighbor-lane shuffle; mask the image pad columns.
    const float mL = (q > 0)  ? 1.0f : 0.0f;
    const float mR = (q < 31) ? 1.0f : 0.0f;

    // Clamped outer row indices (out-of-range rows are weight-masked to zero).
    const int hm = (h0 > 0)      ? h0 - 1 : h0;
    const int hp = (h1 < HH - 1) ? h1 + 1 : h1;

    const float* xbase = x   + (size_t)(b * CHN + g * CG) * HW + w0;
    float*       obase = out + (size_t)(b * CHN + g * CG) * HW + (size_t)h0 * WW + w0;

#pragma unroll
    for (int cg = 0; cg < CG; ++cg) {
        const float* xc = xbase + (size_t)cg * HW;
        float4 rm = *(const float4*)(xc + (size_t)hm * WW);
        float4 r0 = *(const float4*)(xc + (size_t)h0 * WW);
        float4 r1 = *(const float4*)(xc + (size_t)h1 * WW);
        float4 rp = *(const float4*)(xc + (size_t)hp * WW);

        // 6-wide row windows: [left, v.x, v.y, v.z, v.w, right] for 4 rows
        float win[4][6];
        win[0][1] = rm.x; win[0][2] = rm.y; win[0][3] = rm.z; win[0][4] = rm.w;
        win[1][1] = r0.x; win[1][2] = r0.y; win[1][3] = r0.z; win[1][4] = r0.w;
        win[2][1] = r1.x; win[2][2] = r1.y; win[2][3] = r1.z; win[2][4] = r1.w;
        win[3][1] = rp.x; win[3][2] = rp.y; win[3][3] = rp.z; win[3][4] = rp.w;
        win[0][0] = __shfl_up(rm.w, 1) * mL;
        win[1][0] = __shfl_up(r0.w, 1) * mL;
        win[2][0] = __shfl_up(r1.w, 1) * mL;
        win[3][0] = __shfl_up(rp.w, 1) * mL;
        win[0][5] = __shfl_down(rm.x, 1) * mR;
        win[1][5] = __shfl_down(r0.x, 1) * mR;
        win[2][5] = __shfl_down(r1.x, 1) * mR;
        win[3][5] = __shfl_down(rp.x, 1) * mR;

        float4 acc0 = make_float4(0.f, 0.f, 0.f, 0.f);  // output row h0: rows m,0,1
        float4 acc1 = make_float4(0.f, 0.f, 0.f, 0.f);  // output row h1: rows 0,1,p
#pragma unroll
        for (int ki = 0; ki < 3; ++ki) {
#pragma unroll
            for (int kj = 0; kj < 3; ++kj) {
                const float4 wv0 = wk0[ki * 3 + kj];
                const float4 wv1 = wk1[ki * 3 + kj];
                acc0.x = fmaf(win[ki    ][0 + kj], wv0.x, acc0.x);
                acc0.y = fmaf(win[ki    ][1 + kj], wv0.y, acc0.y);
                acc0.z = fmaf(win[ki    ][2 + kj], wv0.z, acc0.z);
                acc0.w = fmaf(win[ki    ][3 + kj], wv0.w, acc0.w);
                acc1.x = fmaf(win[ki + 1][0 + kj], wv1.x, acc1.x);
                acc1.y = fmaf(win[ki + 1][1 + kj], wv1.y, acc1.y);
                acc1.z = fmaf(win[ki + 1][2 + kj], wv1.z, acc1.z);
                acc1.w = fmaf(win[ki + 1][3 + kj], wv1.w, acc1.w);
            }
        }

        *(float4*)(obase + (size_t)cg * HW)      = acc0;
        *(float4*)(obase + (size_t)cg * HW + WW) = acc1;
    }
}

extern "C" void kernel_launch(void* const* d_in, const int* in_sizes, int n_in,
                              void* d_out, int out_size, void* d_ws, size_t ws_size,
                              hipStream_t stream) {
    const float* x = (const float*)d_in[0];
    const float* w = (const float*)d_in[1];
    float* out = (float*)d_out;

    // total threads = B * G * (H/2) * (W/4) = 131072
    const int total = BATCH * GRP * (HH / 2) * (WW / 4);
    const int block = 256;
    const int grid = total / block;   // 512

    // Launch TWICE (idempotent). dur_us delta vs previous round isolates one
    // L3-hot kernel invocation for bottleneck attribution.
    ska_small_kernel<<<grid, block, 0, stream>>>(x, w, out);
    ska_small_kernel<<<grid, block, 0, stream>>>(x, w, out);
}

// Round 6
// 106.969 us; speedup vs baseline: 1.1455x; 1.1455x over previous
//
#include <hip/hip_runtime.h>
#include <hip/hip_bf16.h>

// Problem constants (match reference setup_inputs)
#define BATCH 8
#define CHN   64
#define GRP   8
#define CG    8      // CHN / GRP
#define HH    128
#define WW    128
#define HW    (HH * WW)   // 16384
// w shape: (B, G, 1, 9, H, W); x/out shape: (B, C, H, W), all fp32.

// Final form (== R4): each thread computes 2 consecutive output rows x one
// aligned float4 quad x all 8 channels of its group.
// tid bits = [b:3][g:3][h2:6][q:5] -> 131072 threads, 512 blocks.
// - 9 dynamic weights loaded once per row-pair, amortized over 8 channels
//   (w HBM fetch = ideal 36 MiB).
// - 2-row register blocking: 4 x-row loads serve 2 output rows (x fetch ~= 2
//   rows/output-row vs 3 unblocked); halo columns come from neighbor lanes via
//   shuffle (zero edge-load instructions); vertical pad folded into weights
//   (branchless, no divergence).
// R5 measurement: one invocation ~= 17.1 us vs ~16.5 us HBM floor for the
// 105 MB minimal traffic -> ~3% off the memory roofline.
__global__ __launch_bounds__(256, 3) void ska_small_kernel(
    const float* __restrict__ x,
    const float* __restrict__ wgt,
    float* __restrict__ out)
{
    int tid = blockIdx.x * blockDim.x + threadIdx.x;
    int q  = tid & 31;           // quad index within row
    int w0 = q * 4;              // aligned float4 column
    int h2 = (tid >> 5) & 63;    // row-pair index
    int g  = (tid >> 11) & 7;
    int b  = tid >> 14;

    const int h0 = h2 * 2;       // even, 0..126
    const int h1 = h0 + 1;       // odd, 1..127

    // ---- 9 dynamic weights for each of the two pixel rows (shared across 8 ch)
    const float* wbase = wgt + ((size_t)(b * GRP + g) * 9) * HW + (size_t)h0 * WW + w0;
    float4 wk0[9], wk1[9];
#pragma unroll
    for (int k = 0; k < 9; ++k) {
        wk0[k] = *(const float4*)(wbase + (size_t)k * HW);
        wk1[k] = *(const float4*)(wbase + (size_t)k * HW + WW);
    }

    // Fold vertical zero-padding into the weights (branchless).
    const float m_top = (h0 > 0)      ? 1.0f : 0.0f;   // row h0's tap-row 0
    const float m_bot = (h1 < HH - 1) ? 1.0f : 0.0f;   // row h1's tap-row 2
#pragma unroll
    for (int j = 0; j < 3; ++j) {
        wk0[j].x     *= m_top; wk0[j].y     *= m_top; wk0[j].z     *= m_top; wk0[j].w     *= m_top;
        wk1[6 + j].x *= m_bot; wk1[6 + j].y *= m_bot; wk1[6 + j].z *= m_bot; wk1[6 + j].w *= m_bot;
    }

    // Horizontal halo via neighbor-lane shuffle; mask the image pad columns.
    const float mL = (q > 0)  ? 1.0f : 0.0f;
    const float mR = (q < 31) ? 1.0f : 0.0f;

    // Clamped outer row indices (out-of-range rows are weight-masked to zero).
    const int hm = (h0 > 0)      ? h0 - 1 : h0;
    const int hp = (h1 < HH - 1) ? h1 + 1 : h1;

    const float* xbase = x   + (size_t)(b * CHN + g * CG) * HW + w0;
    float*       obase = out + (size_t)(b * CHN + g * CG) * HW + (size_t)h0 * WW + w0;

#pragma unroll
    for (int cg = 0; cg < CG; ++cg) {
        const float* xc = xbase + (size_t)cg * HW;
        float4 rm = *(const float4*)(xc + (size_t)hm * WW);
        float4 r0 = *(const float4*)(xc + (size_t)h0 * WW);
        float4 r1 = *(const float4*)(xc + (size_t)h1 * WW);
        float4 rp = *(const float4*)(xc + (size_t)hp * WW);

        // 6-wide row windows: [left, v.x, v.y, v.z, v.w, right] for 4 rows
        float win[4][6];
        win[0][1] = rm.x; win[0][2] = rm.y; win[0][3] = rm.z; win[0][4] = rm.w;
        win[1][1] = r0.x; win[1][2] = r0.y; win[1][3] = r0.z; win[1][4] = r0.w;
        win[2][1] = r1.x; win[2][2] = r1.y; win[2][3] = r1.z; win[2][4] = r1.w;
        win[3][1] = rp.x; win[3][2] = rp.y; win[3][3] = rp.z; win[3][4] = rp.w;
        win[0][0] = __shfl_up(rm.w, 1) * mL;
        win[1][0] = __shfl_up(r0.w, 1) * mL;
        win[2][0] = __shfl_up(r1.w, 1) * mL;
        win[3][0] = __shfl_up(rp.w, 1) * mL;
        win[0][5] = __shfl_down(rm.x, 1) * mR;
        win[1][5] = __shfl_down(r0.x, 1) * mR;
        win[2][5] = __shfl_down(r1.x, 1) * mR;
        win[3][5] = __shfl_down(rp.x, 1) * mR;

        float4 acc0 = make_float4(0.f, 0.f, 0.f, 0.f);  // output row h0: rows m,0,1
        float4 acc1 = make_float4(0.f, 0.f, 0.f, 0.f);  // output row h1: rows 0,1,p
#pragma unroll
        for (int ki = 0; ki < 3; ++ki) {
#pragma unroll
            for (int kj = 0; kj < 3; ++kj) {
                const float4 wv0 = wk0[ki * 3 + kj];
                const float4 wv1 = wk1[ki * 3 + kj];
                acc0.x = fmaf(win[ki    ][0 + kj], wv0.x, acc0.x);
                acc0.y = fmaf(win[ki    ][1 + kj], wv0.y, acc0.y);
                acc0.z = fmaf(win[ki    ][2 + kj], wv0.z, acc0.z);
                acc0.w = fmaf(win[ki    ][3 + kj], wv0.w, acc0.w);
                acc1.x = fmaf(win[ki + 1][0 + kj], wv1.x, acc1.x);
                acc1.y = fmaf(win[ki + 1][1 + kj], wv1.y, acc1.y);
                acc1.z = fmaf(win[ki + 1][2 + kj], wv1.z, acc1.z);
                acc1.w = fmaf(win[ki + 1][3 + kj], wv1.w, acc1.w);
            }
        }

        *(float4*)(obase + (size_t)cg * HW)      = acc0;
        *(float4*)(obase + (size_t)cg * HW + WW) = acc1;
    }
}

extern "C" void kernel_launch(void* const* d_in, const int* in_sizes, int n_in,
                              void* d_out, int out_size, void* d_ws, size_t ws_size,
                              hipStream_t stream) {
    const float* x = (const float*)d_in[0];
    const float* w = (const float*)d_in[1];
    float* out = (float*)d_out;

    // total threads = B * G * (H/2) * (W/4) = 131072
    const int total = BATCH * GRP * (HH / 2) * (WW / 4);
    const int block = 256;
    const int grid = total / block;   // 512
    ska_small_kernel<<<grid, block, 0, stream>>>(x, w, out);
}